// Round 1
// baseline (250.453 us; speedup 1.0000x reference)
//
#include <hip/hip_runtime.h>

// QCNN simulation: 8 qubits, 256 amplitudes, one wave (64 lanes) per batch element.
// Lane l holds amplitudes i = (l<<2)|j, j=0..3.
// Qubit q <-> bit (7-q) of amplitude index i:
//   q=0..5 -> lane bits 5..0 (cross-lane via shfl_xor)
//   q=6    -> j bit 1 (in-register)
//   q=7    -> j bit 0 (in-register)
// Phase 1 (4x RY+CNOT cycles) is purely REAL (RY real, CNOT permutation, |0> real).
// Phase 2 (CRX/U3 layers) is complex.

#define NQ 8

__device__ __forceinline__ float shflx(float v, int mask) {
    return __shfl_xor(v, mask, 64);
}

__global__ __launch_bounds__(256) void qcnn_kernel(
    const float* __restrict__ x,
    const float* __restrict__ crx_theta,
    const float* __restrict__ u3p,
    const float* __restrict__ w1,
    const float* __restrict__ b1,
    const float* __restrict__ w2,
    const float* __restrict__ b2,
    float* __restrict__ out,
    int Btot)
{
    const int gtid = blockIdx.x * blockDim.x + threadIdx.x;
    const int wave = gtid >> 6;
    const int l = threadIdx.x & 63;
    if (wave >= Btot) return;

    // ---- per-element RY coefficients (same angles reused every cycle) ----
    float c[NQ], s[NQ];
#pragma unroll
    for (int q = 0; q < NQ; ++q) {
        float half = 0.5f * x[wave * NQ + q];
        __sincosf(half, &s[q], &c[q]);
    }

    // ---- uniform gate constants ----
    float crc[2], crs[2];
#pragma unroll
    for (int L = 0; L < 2; ++L) {
        __sincosf(0.5f * crx_theta[L], &crs[L], &crc[L]);
    }
    // U3 matrix: [[ct, -e^{i lm} st], [e^{i ph} st, e^{i(ph+lm)} ct]]
    float u_ct[2], u01r[2], u01i[2], u10r[2], u10i[2], u11r[2], u11i[2];
#pragma unroll
    for (int L = 0; L < 2; ++L) {
        float th = u3p[3 * L], ph = u3p[3 * L + 1], lm = u3p[3 * L + 2];
        float st_, ct_, sl, cl, sp, cp, spl, cpl;
        __sincosf(0.5f * th, &st_, &ct_);
        __sincosf(lm, &sl, &cl);
        __sincosf(ph, &sp, &cp);
        __sincosf(ph + lm, &spl, &cpl);
        u_ct[L] = ct_;
        u01r[L] = -st_ * cl; u01i[L] = -st_ * sl;
        u10r[L] =  st_ * cp; u10i[L] =  st_ * sp;
        u11r[L] =  ct_ * cpl; u11i[L] = ct_ * spl;
    }

    // ================= Phase 1: real state =================
    float a0 = (l == 0) ? 1.0f : 0.0f, a1 = 0.0f, a2 = 0.0f, a3 = 0.0f;
#pragma unroll
    for (int cyc = 0; cyc < 4; ++cyc) {
        // RY on qubits 0..5 (lane bits): new = c*mine + (bit? s : -s)*partner
#pragma unroll
        for (int q = 0; q < 6; ++q) {
            const int sh = 5 - q, m = 1 << sh;
            const float t = ((l >> sh) & 1) ? s[q] : -s[q];
            float o0 = shflx(a0, m), o1 = shflx(a1, m), o2 = shflx(a2, m), o3 = shflx(a3, m);
            a0 = fmaf(c[q], a0, t * o0);
            a1 = fmaf(c[q], a1, t * o1);
            a2 = fmaf(c[q], a2, t * o2);
            a3 = fmaf(c[q], a3, t * o3);
        }
        { // RY q=6: pairs (a0,a2),(a1,a3)
            float n0 = c[6]*a0 - s[6]*a2, n1 = c[6]*a1 - s[6]*a3;
            float n2 = s[6]*a0 + c[6]*a2, n3 = s[6]*a1 + c[6]*a3;
            a0 = n0; a1 = n1; a2 = n2; a3 = n3;
        }
        { // RY q=7: pairs (a0,a1),(a2,a3)
            float n0 = c[7]*a0 - s[7]*a1, n1 = s[7]*a0 + c[7]*a1;
            float n2 = c[7]*a2 - s[7]*a3, n3 = s[7]*a2 + c[7]*a3;
            a0 = n0; a1 = n1; a2 = n2; a3 = n3;
        }
        // CNOT ring [q, q+1]
#pragma unroll
        for (int q = 0; q < 5; ++q) { // control lane bit (5-q), target lane bit (4-q)
            const int csh = 5 - q, tm = 1 << (4 - q);
            const bool ct = (l >> csh) & 1;
            float o0 = shflx(a0, tm), o1 = shflx(a1, tm), o2 = shflx(a2, tm), o3 = shflx(a3, tm);
            a0 = ct ? o0 : a0; a1 = ct ? o1 : a1; a2 = ct ? o2 : a2; a3 = ct ? o3 : a3;
        }
        { // CNOT q=5: control lane bit0, target j bit1 -> swap (a0,a2),(a1,a3) if l&1
            const bool ct = l & 1;
            float t0 = ct ? a2 : a0, t2 = ct ? a0 : a2;
            float t1 = ct ? a3 : a1, t3 = ct ? a1 : a3;
            a0 = t0; a1 = t1; a2 = t2; a3 = t3;
        }
        { // CNOT q=6: control j bit1, target j bit0 -> swap a2<->a3
            float t = a2; a2 = a3; a3 = t;
        }
        // CNOT q=7: control j bit0, target lane bit5 -> odd-j amplitudes swap across l^32
        a1 = shflx(a1, 32);
        a3 = shflx(a3, 32);
    }

    // ================= Phase 2: complex state =================
    float re0 = a0, re1 = a1, re2 = a2, re3 = a3;
    float im0 = 0.f, im1 = 0.f, im2 = 0.f, im3 = 0.f;

    // CRX (control, target both lane bits). Gate on control=1 subspace:
    // [[c, -i sn],[-i sn, c]] -> new_re = c*re + sn*im_partner; new_im = c*im - sn*re_partner
    auto crx_ll = [&](int csh, int tm, float cc, float sn) {
        const bool ct = (l >> csh) & 1;
        float ro0 = shflx(re0, tm), io0 = shflx(im0, tm);
        float ro1 = shflx(re1, tm), io1 = shflx(im1, tm);
        float ro2 = shflx(re2, tm), io2 = shflx(im2, tm);
        float ro3 = shflx(re3, tm), io3 = shflx(im3, tm);
        if (ct) {
            re0 = cc*re0 + sn*io0; im0 = cc*im0 - sn*ro0;
            re1 = cc*re1 + sn*io1; im1 = cc*im1 - sn*ro1;
            re2 = cc*re2 + sn*io2; im2 = cc*im2 - sn*ro2;
            re3 = cc*re3 + sn*io3; im3 = cc*im3 - sn*ro3;
        }
    };
    auto crx_67 = [&](float cc, float sn) { // control j bit1 (j=2,3), target j bit0: pair (2,3)
        float nr2 = cc*re2 + sn*im3, ni2 = cc*im2 - sn*re3;
        float nr3 = cc*re3 + sn*im2, ni3 = cc*im3 - sn*re2;
        re2 = nr2; im2 = ni2; re3 = nr3; im3 = ni3;
    };
    auto crx_56 = [&](float cc, float sn) { // control lane bit0, target j bit1: pairs (0,2),(1,3)
        if (l & 1) {
            float nr0 = cc*re0 + sn*im2, ni0 = cc*im0 - sn*re2;
            float nr2 = cc*re2 + sn*im0, ni2 = cc*im2 - sn*re0;
            float nr1 = cc*re1 + sn*im3, ni1 = cc*im1 - sn*re3;
            float nr3 = cc*re3 + sn*im1, ni3 = cc*im3 - sn*re1;
            re0 = nr0; im0 = ni0; re1 = nr1; im1 = ni1;
            re2 = nr2; im2 = ni2; re3 = nr3; im3 = ni3;
        }
    };
    auto crx_57 = [&](float cc, float sn) { // control lane bit0, target j bit0: pairs (0,1),(2,3)
        if (l & 1) {
            float nr0 = cc*re0 + sn*im1, ni0 = cc*im0 - sn*re1;
            float nr1 = cc*re1 + sn*im0, ni1 = cc*im1 - sn*re0;
            float nr2 = cc*re2 + sn*im3, ni2 = cc*im2 - sn*re3;
            float nr3 = cc*re3 + sn*im2, ni3 = cc*im3 - sn*re2;
            re0 = nr0; im0 = ni0; re1 = nr1; im1 = ni1;
            re2 = nr2; im2 = ni2; re3 = nr3; im3 = ni3;
        }
    };
    // U3 on a lane-bit qubit: new = A*mine + B*partner,
    // bit=0: A=m00=(ct,0), B=m01 ; bit=1: A=m11, B=m10
    auto u3_lane = [&](int sh, int L) {
        const int m = 1 << sh;
        const bool b = (l >> sh) & 1;
        const float Ar = b ? u11r[L] : u_ct[L];
        const float Ai = b ? u11i[L] : 0.0f;
        const float Br = b ? u10r[L] : u01r[L];
        const float Bi = b ? u10i[L] : u01i[L];
        float ro0 = shflx(re0, m), io0 = shflx(im0, m);
        float ro1 = shflx(re1, m), io1 = shflx(im1, m);
        float ro2 = shflx(re2, m), io2 = shflx(im2, m);
        float ro3 = shflx(re3, m), io3 = shflx(im3, m);
        float nr0 = Ar*re0 - Ai*im0 + Br*ro0 - Bi*io0;
        float ni0 = Ar*im0 + Ai*re0 + Br*io0 + Bi*ro0;
        float nr1 = Ar*re1 - Ai*im1 + Br*ro1 - Bi*io1;
        float ni1 = Ar*im1 + Ai*re1 + Br*io1 + Bi*ro1;
        float nr2 = Ar*re2 - Ai*im2 + Br*ro2 - Bi*io2;
        float ni2 = Ar*im2 + Ai*re2 + Br*io2 + Bi*ro2;
        float nr3 = Ar*re3 - Ai*im3 + Br*ro3 - Bi*io3;
        float ni3 = Ar*im3 + Ai*re3 + Br*io3 + Bi*ro3;
        re0 = nr0; im0 = ni0; re1 = nr1; im1 = ni1;
        re2 = nr2; im2 = ni2; re3 = nr3; im3 = ni3;
    };
    auto u3_q7 = [&](int L) { // j bit0: pairs (0,1),(2,3)
        const float ctr = u_ct[L];
        const float m01r = u01r[L], m01i = u01i[L];
        const float m10r = u10r[L], m10i = u10i[L];
        const float m11r = u11r[L], m11i = u11i[L];
        float nr0 = ctr*re0 + m01r*re1 - m01i*im1;
        float ni0 = ctr*im0 + m01r*im1 + m01i*re1;
        float nr1 = m10r*re0 - m10i*im0 + m11r*re1 - m11i*im1;
        float ni1 = m10r*im0 + m10i*re0 + m11r*im1 + m11i*re1;
        float nr2 = ctr*re2 + m01r*re3 - m01i*im3;
        float ni2 = ctr*im2 + m01r*im3 + m01i*re3;
        float nr3 = m10r*re2 - m10i*im2 + m11r*re3 - m11i*im3;
        float ni3 = m10r*im2 + m10i*re2 + m11r*im3 + m11i*re3;
        re0 = nr0; im0 = ni0; re1 = nr1; im1 = ni1;
        re2 = nr2; im2 = ni2; re3 = nr3; im3 = ni3;
    };

    // Layer 0: CRX pairs (0,1),(2,3),(4,5),(6,7) then (1,2),(3,4),(5,6); U3 on 1,3,5,7
    crx_ll(5, 16, crc[0], crs[0]); // (0,1)
    crx_ll(3, 4,  crc[0], crs[0]); // (2,3)
    crx_ll(1, 1,  crc[0], crs[0]); // (4,5)
    crx_67(crc[0], crs[0]);        // (6,7)
    crx_ll(4, 8,  crc[0], crs[0]); // (1,2)
    crx_ll(2, 2,  crc[0], crs[0]); // (3,4)
    crx_56(crc[0], crs[0]);        // (5,6)
    u3_lane(4, 0);                 // q=1
    u3_lane(2, 0);                 // q=3
    u3_lane(0, 0);                 // q=5
    u3_q7(0);                      // q=7
    // Layer 1: CRX (1,3),(5,7) then (3,5); U3 on 3,7
    crx_ll(4, 4, crc[1], crs[1]);  // (1,3)
    crx_57(crc[1], crs[1]);        // (5,7)
    crx_ll(2, 1, crc[1], crs[1]);  // (3,5)
    u3_lane(2, 1);                 // q=3
    u3_q7(1);                      // q=7

    // ================= expvals + MLP =================
    float n0 = re0*re0 + im0*im0;
    float n1 = re1*re1 + im1*im1;
    float n2 = re2*re2 + im2*im2;
    float n3 = re3*re3 + im3*im3;
    // Z(q=3): sign from lane bit2 (uniform over j). Z(q=7): sign from j bit0.
    float f0 = (((l >> 2) & 1) ? -1.0f : 1.0f) * (n0 + n1 + n2 + n3);
    float f1 = (n0 - n1) + (n2 - n3);
#pragma unroll
    for (int m = 32; m >= 1; m >>= 1) {
        f0 += shflx(f0, m);
        f1 += shflx(f1, m);
    }

    if (l == 0) {
        float acc = b2[0];
#pragma unroll
        for (int k = 0; k < 10; ++k) {
            float h = tanhf(fmaf(f0, w1[k], fmaf(f1, w1[10 + k], b1[k])));
            acc = fmaf(h, w2[k], acc);
        }
        out[wave] = 1.0f / (1.0f + expf(-acc));
    }
}

extern "C" void kernel_launch(void* const* d_in, const int* in_sizes, int n_in,
                              void* d_out, int out_size, void* d_ws, size_t ws_size,
                              hipStream_t stream) {
    const float* x   = (const float*)d_in[0];
    const float* crx = (const float*)d_in[1];
    const float* u3p = (const float*)d_in[2];
    const float* w1  = (const float*)d_in[3];
    const float* b1  = (const float*)d_in[4];
    const float* w2  = (const float*)d_in[5];
    const float* b2  = (const float*)d_in[6];
    float* out = (float*)d_out;

    const int B = in_sizes[0] / NQ;          // 65536
    const int wavesPerBlock = 256 / 64;      // 4
    const int grid = (B + wavesPerBlock - 1) / wavesPerBlock;
    hipLaunchKernelGGL(qcnn_kernel, dim3(grid), dim3(256), 0, stream,
                       x, crx, u3p, w1, b1, w2, b2, out, B);
}

// Round 2
// 175.001 us; speedup vs baseline: 1.4312x; 1.4312x over previous
//
#include <hip/hip_runtime.h>

// QCNN simulation: 8 qubits, 256 amplitudes, one wave (64 lanes) per batch element.
// Lane l holds amplitudes i = (l<<2)|j, j=0..3.
// Qubit q <-> bit (7-q) of amplitude index i:
//   q=0..5 -> lane bits 5..0 (cross-lane), q=6 -> j bit 1, q=7 -> j bit 0.
// Phase 1 (4x RY+CNOT cycles) is purely REAL. Phase 2 (CRX/U3) is complex.
//
// R1 change: Round-0 was ds-pipe-bound (VALUBusy 51%, all shuffles = ds_bpermute).
// Cross-lane xor masks 1,2,4,8 now use DPP (VALU pipe):
//   xor1 = quad_perm[1,0,3,2] (0xB1); xor2 = quad_perm[2,3,0,1] (0x4E);
//   xor4 = ROW_HALF_MIRROR(xor7) o quad_perm[3,2,1,0](xor3); xor8 = row_ror:8 (0x128).
// xor16 = ds_swizzle (one ds op), xor32 = ds_bpermute (unavoidable cross-half).
// ds ops/wave: 276 -> ~76. MLP tail parallelized over 16 lanes with fast exp.

#define NQ 8

template<int CTRL>
__device__ __forceinline__ float dppf(float v) {
    return __int_as_float(__builtin_amdgcn_mov_dpp(__float_as_int(v), CTRL, 0xF, 0xF, true));
}

template<int M>
__device__ __forceinline__ float sx(float v) {
    if constexpr (M == 1)       return dppf<0xB1>(v);                 // quad_perm [1,0,3,2]
    else if constexpr (M == 2)  return dppf<0x4E>(v);                 // quad_perm [2,3,0,1]
    else if constexpr (M == 4)  return dppf<0x1B>(dppf<0x141>(v));    // xor7 then xor3
    else if constexpr (M == 8)  return dppf<0x128>(v);                // row_ror:8
    else if constexpr (M == 16) return __int_as_float(__builtin_amdgcn_ds_swizzle(__float_as_int(v), 0x401F));
    else                        return __shfl_xor(v, 32, 64);         // cross-half: bpermute
}

#define RY_L(q, M) do { \
    const float tq = ((l >> (5-(q))) & 1) ? s[(q)] : -s[(q)]; \
    const float cq = c[(q)]; \
    float o0 = sx<M>(a0), o1 = sx<M>(a1), o2 = sx<M>(a2), o3 = sx<M>(a3); \
    a0 = fmaf(cq, a0, tq*o0); a1 = fmaf(cq, a1, tq*o1); \
    a2 = fmaf(cq, a2, tq*o2); a3 = fmaf(cq, a3, tq*o3); \
} while(0)

#define CNOT_LL(CSH, M) do { \
    const bool ct = (l >> (CSH)) & 1; \
    float o0 = sx<M>(a0), o1 = sx<M>(a1), o2 = sx<M>(a2), o3 = sx<M>(a3); \
    a0 = ct ? o0 : a0; a1 = ct ? o1 : a1; a2 = ct ? o2 : a2; a3 = ct ? o3 : a3; \
} while(0)

#define SHFL8(M) \
    float ro0=sx<M>(re0), io0=sx<M>(im0), ro1=sx<M>(re1), io1=sx<M>(im1), \
          ro2=sx<M>(re2), io2=sx<M>(im2), ro3=sx<M>(re3), io3=sx<M>(im3);

#define CRX_LL(CSH, M, cc, sn) do { \
    const bool ct = (l >> (CSH)) & 1; \
    SHFL8(M) \
    if (ct) { \
        re0 = cc*re0 + sn*io0; im0 = cc*im0 - sn*ro0; \
        re1 = cc*re1 + sn*io1; im1 = cc*im1 - sn*ro1; \
        re2 = cc*re2 + sn*io2; im2 = cc*im2 - sn*ro2; \
        re3 = cc*re3 + sn*io3; im3 = cc*im3 - sn*ro3; \
    } \
} while(0)

#define U3_LANE(SH, M, L) do { \
    const bool b = (l >> (SH)) & 1; \
    const float Ar = b ? u11r[L] : u_ct[L]; \
    const float Ai = b ? u11i[L] : 0.0f; \
    const float Br = b ? u10r[L] : u01r[L]; \
    const float Bi = b ? u10i[L] : u01i[L]; \
    SHFL8(M) \
    float nr0 = Ar*re0 - Ai*im0 + Br*ro0 - Bi*io0; \
    float ni0 = Ar*im0 + Ai*re0 + Br*io0 + Bi*ro0; \
    float nr1 = Ar*re1 - Ai*im1 + Br*ro1 - Bi*io1; \
    float ni1 = Ar*im1 + Ai*re1 + Br*io1 + Bi*ro1; \
    float nr2 = Ar*re2 - Ai*im2 + Br*ro2 - Bi*io2; \
    float ni2 = Ar*im2 + Ai*re2 + Br*io2 + Bi*ro2; \
    float nr3 = Ar*re3 - Ai*im3 + Br*ro3 - Bi*io3; \
    float ni3 = Ar*im3 + Ai*re3 + Br*io3 + Bi*ro3; \
    re0 = nr0; im0 = ni0; re1 = nr1; im1 = ni1; \
    re2 = nr2; im2 = ni2; re3 = nr3; im3 = ni3; \
} while(0)

__global__ __launch_bounds__(256) void qcnn_kernel(
    const float* __restrict__ x,
    const float* __restrict__ crx_theta,
    const float* __restrict__ u3p,
    const float* __restrict__ w1,
    const float* __restrict__ b1,
    const float* __restrict__ w2,
    const float* __restrict__ b2,
    float* __restrict__ out,
    int Btot)
{
    const int gtid = blockIdx.x * blockDim.x + threadIdx.x;
    const int wave = gtid >> 6;
    const int l = threadIdx.x & 63;
    if (wave >= Btot) return;

    // ---- per-element RY coefficients (same angles reused every cycle) ----
    float c[NQ], s[NQ];
#pragma unroll
    for (int q = 0; q < NQ; ++q) {
        float half = 0.5f * x[wave * NQ + q];
        __sincosf(half, &s[q], &c[q]);
    }

    // ---- uniform gate constants ----
    float crc[2], crs[2];
#pragma unroll
    for (int L = 0; L < 2; ++L) {
        __sincosf(0.5f * crx_theta[L], &crs[L], &crc[L]);
    }
    // U3 matrix: [[ct, -e^{i lm} st], [e^{i ph} st, e^{i(ph+lm)} ct]]
    float u_ct[2], u01r[2], u01i[2], u10r[2], u10i[2], u11r[2], u11i[2];
#pragma unroll
    for (int L = 0; L < 2; ++L) {
        float th = u3p[3 * L], ph = u3p[3 * L + 1], lm = u3p[3 * L + 2];
        float st_, ct_, sl, cl, sp, cp, spl, cpl;
        __sincosf(0.5f * th, &st_, &ct_);
        __sincosf(lm, &sl, &cl);
        __sincosf(ph, &sp, &cp);
        __sincosf(ph + lm, &spl, &cpl);
        u_ct[L] = ct_;
        u01r[L] = -st_ * cl; u01i[L] = -st_ * sl;
        u10r[L] =  st_ * cp; u10i[L] =  st_ * sp;
        u11r[L] =  ct_ * cpl; u11i[L] = ct_ * spl;
    }

    // ================= Phase 1: real state =================
    float a0 = (l == 0) ? 1.0f : 0.0f, a1 = 0.0f, a2 = 0.0f, a3 = 0.0f;
#pragma unroll
    for (int cyc = 0; cyc < 4; ++cyc) {
        // RY on lane qubits 0..5 (masks 32,16,8,4,2,1)
        RY_L(0, 32); RY_L(1, 16); RY_L(2, 8); RY_L(3, 4); RY_L(4, 2); RY_L(5, 1);
        { // RY q=6: pairs (a0,a2),(a1,a3)
            float n0 = c[6]*a0 - s[6]*a2, n1 = c[6]*a1 - s[6]*a3;
            float n2 = s[6]*a0 + c[6]*a2, n3 = s[6]*a1 + c[6]*a3;
            a0 = n0; a1 = n1; a2 = n2; a3 = n3;
        }
        { // RY q=7: pairs (a0,a1),(a2,a3)
            float n0 = c[7]*a0 - s[7]*a1, n1 = s[7]*a0 + c[7]*a1;
            float n2 = c[7]*a2 - s[7]*a3, n3 = s[7]*a2 + c[7]*a3;
            a0 = n0; a1 = n1; a2 = n2; a3 = n3;
        }
        // CNOT ring: (0,1)..(4,5) are lane-lane
        CNOT_LL(5, 16); CNOT_LL(4, 8); CNOT_LL(3, 4); CNOT_LL(2, 2); CNOT_LL(1, 1);
        { // CNOT q=5: control lane bit0, target j bit1 -> swap (a0,a2),(a1,a3) if l&1
            const bool ct = l & 1;
            float t0 = ct ? a2 : a0, t2 = ct ? a0 : a2;
            float t1 = ct ? a3 : a1, t3 = ct ? a1 : a3;
            a0 = t0; a1 = t1; a2 = t2; a3 = t3;
        }
        { // CNOT q=6: control j bit1, target j bit0 -> swap a2<->a3
            float t = a2; a2 = a3; a3 = t;
        }
        // CNOT q=7: control j bit0, target lane bit5 -> odd-j amplitudes swap across l^32
        a1 = sx<32>(a1);
        a3 = sx<32>(a3);
    }

    // ================= Phase 2: complex state =================
    float re0 = a0, re1 = a1, re2 = a2, re3 = a3;
    float im0 = 0.f, im1 = 0.f, im2 = 0.f, im3 = 0.f;

    // Layer 0: CRX pairs (0,1),(2,3),(4,5),(6,7) then (1,2),(3,4),(5,6); U3 on 1,3,5,7
    CRX_LL(5, 16, crc[0], crs[0]); // (0,1)
    CRX_LL(3, 4,  crc[0], crs[0]); // (2,3)
    CRX_LL(1, 1,  crc[0], crs[0]); // (4,5)
    { // (6,7): control j bit1, target j bit0: pair (2,3)
        const float cc = crc[0], sn = crs[0];
        float nr2 = cc*re2 + sn*im3, ni2 = cc*im2 - sn*re3;
        float nr3 = cc*re3 + sn*im2, ni3 = cc*im3 - sn*re2;
        re2 = nr2; im2 = ni2; re3 = nr3; im3 = ni3;
    }
    CRX_LL(4, 8,  crc[0], crs[0]); // (1,2)
    CRX_LL(2, 2,  crc[0], crs[0]); // (3,4)
    { // (5,6): control lane bit0, target j bit1: pairs (0,2),(1,3)
        const float cc = crc[0], sn = crs[0];
        if (l & 1) {
            float nr0 = cc*re0 + sn*im2, ni0 = cc*im0 - sn*re2;
            float nr2 = cc*re2 + sn*im0, ni2 = cc*im2 - sn*re0;
            float nr1 = cc*re1 + sn*im3, ni1 = cc*im1 - sn*re3;
            float nr3 = cc*re3 + sn*im1, ni3 = cc*im3 - sn*re1;
            re0 = nr0; im0 = ni0; re1 = nr1; im1 = ni1;
            re2 = nr2; im2 = ni2; re3 = nr3; im3 = ni3;
        }
    }
    U3_LANE(4, 16, 0);             // q=1
    U3_LANE(2, 4,  0);             // q=3
    U3_LANE(0, 1,  0);             // q=5
    { // U3 q=7 (j bit0): pairs (0,1),(2,3)
        const int L = 0;
        const float ctr = u_ct[L];
        const float m01r = u01r[L], m01i = u01i[L];
        const float m10r = u10r[L], m10i = u10i[L];
        const float m11r = u11r[L], m11i = u11i[L];
        float nr0 = ctr*re0 + m01r*re1 - m01i*im1;
        float ni0 = ctr*im0 + m01r*im1 + m01i*re1;
        float nr1 = m10r*re0 - m10i*im0 + m11r*re1 - m11i*im1;
        float ni1 = m10r*im0 + m10i*re0 + m11r*im1 + m11i*re1;
        float nr2 = ctr*re2 + m01r*re3 - m01i*im3;
        float ni2 = ctr*im2 + m01r*im3 + m01i*re3;
        float nr3 = m10r*re2 - m10i*im2 + m11r*re3 - m11i*im3;
        float ni3 = m10r*im2 + m10i*re2 + m11r*im3 + m11i*re3;
        re0 = nr0; im0 = ni0; re1 = nr1; im1 = ni1;
        re2 = nr2; im2 = ni2; re3 = nr3; im3 = ni3;
    }
    // Layer 1: CRX (1,3),(5,7) then (3,5); U3 on 3,7
    CRX_LL(4, 4, crc[1], crs[1]);  // (1,3)
    { // (5,7): control lane bit0, target j bit0: pairs (0,1),(2,3)
        const float cc = crc[1], sn = crs[1];
        if (l & 1) {
            float nr0 = cc*re0 + sn*im1, ni0 = cc*im0 - sn*re1;
            float nr1 = cc*re1 + sn*im0, ni1 = cc*im1 - sn*re0;
            float nr2 = cc*re2 + sn*im3, ni2 = cc*im2 - sn*re3;
            float nr3 = cc*re3 + sn*im2, ni3 = cc*im3 - sn*re2;
            re0 = nr0; im0 = ni0; re1 = nr1; im1 = ni1;
            re2 = nr2; im2 = ni2; re3 = nr3; im3 = ni3;
        }
    }
    CRX_LL(2, 1, crc[1], crs[1]);  // (3,5)
    U3_LANE(2, 4, 1);              // q=3
    { // U3 q=7, layer 1
        const int L = 1;
        const float ctr = u_ct[L];
        const float m01r = u01r[L], m01i = u01i[L];
        const float m10r = u10r[L], m10i = u10i[L];
        const float m11r = u11r[L], m11i = u11i[L];
        float nr0 = ctr*re0 + m01r*re1 - m01i*im1;
        float ni0 = ctr*im0 + m01r*im1 + m01i*re1;
        float nr1 = m10r*re0 - m10i*im0 + m11r*re1 - m11i*im1;
        float ni1 = m10r*im0 + m10i*re0 + m11r*im1 + m11i*re1;
        float nr2 = ctr*re2 + m01r*re3 - m01i*im3;
        float ni2 = ctr*im2 + m01r*im3 + m01i*re3;
        float nr3 = m10r*re2 - m10i*im2 + m11r*re3 - m11i*im3;
        float ni3 = m10r*im2 + m10i*re2 + m11r*im3 + m11i*re3;
        re0 = nr0; im0 = ni0; re1 = nr1; im1 = ni1;
        re2 = nr2; im2 = ni2; re3 = nr3; im3 = ni3;
    }

    // ================= expvals + MLP =================
    float n0 = re0*re0 + im0*im0;
    float n1 = re1*re1 + im1*im1;
    float n2 = re2*re2 + im2*im2;
    float n3 = re3*re3 + im3*im3;
    // Z(q=3): sign from lane bit2. Z(q=7): sign from j bit0.
    float f0 = (((l >> 2) & 1) ? -1.0f : 1.0f) * (n0 + n1 + n2 + n3);
    float f1 = (n0 - n1) + (n2 - n3);
    f0 += sx<1>(f0);  f1 += sx<1>(f1);
    f0 += sx<2>(f0);  f1 += sx<2>(f1);
    f0 += sx<4>(f0);  f1 += sx<4>(f1);
    f0 += sx<8>(f0);  f1 += sx<8>(f1);
    f0 += sx<16>(f0); f1 += sx<16>(f1);
    f0 += sx<32>(f0); f1 += sx<32>(f1);

    // MLP tail: 10 hidden units spread over lanes 0..9 of each 16-lane row.
    const int k = l & 15;
    float contrib = 0.0f;
    if (k < 10) {
        float z = fmaf(f0, w1[k], fmaf(f1, w1[10 + k], b1[k]));
        float e = __expf(2.0f * z);          // tanh(z) = (e^{2z}-1)/(e^{2z}+1)
        float h = (e - 1.0f) / (e + 1.0f);
        contrib = h * w2[k];
    }
    contrib += sx<1>(contrib);
    contrib += sx<2>(contrib);
    contrib += sx<4>(contrib);
    contrib += sx<8>(contrib);
    if (l == 0) {
        float a = contrib + b2[0];
        out[wave] = 1.0f / (1.0f + __expf(-a));
    }
}

extern "C" void kernel_launch(void* const* d_in, const int* in_sizes, int n_in,
                              void* d_out, int out_size, void* d_ws, size_t ws_size,
                              hipStream_t stream) {
    const float* x   = (const float*)d_in[0];
    const float* crx = (const float*)d_in[1];
    const float* u3p = (const float*)d_in[2];
    const float* w1  = (const float*)d_in[3];
    const float* b1  = (const float*)d_in[4];
    const float* w2  = (const float*)d_in[5];
    const float* b2  = (const float*)d_in[6];
    float* out = (float*)d_out;

    const int B = in_sizes[0] / NQ;          // 65536
    const int wavesPerBlock = 256 / 64;      // 4
    const int grid = (B + wavesPerBlock - 1) / wavesPerBlock;
    hipLaunchKernelGGL(qcnn_kernel, dim3(grid), dim3(256), 0, stream,
                       x, crx, u3p, w1, b1, w2, b2, out, B);
}

// Round 4
// 152.764 us; speedup vs baseline: 1.6395x; 1.1456x over previous
//
#include <hip/hip_runtime.h>

// QCNN: 8 qubits, 256 amplitudes, one wave per batch element.
// Lane l holds amplitudes i = (l<<2)|j, j=0..3. Qubit q <-> bit (7-q) of i:
// q=0..5 -> lane bits 5..0, q=6 -> j bit1, q=7 -> j bit0.
//
// R2 structure (VALU-issue-bound; minimize instruction count):
//  - cycle-1 RY computed analytically from |0> product state
//  - CNOT ring fused into ONE linear-map permutation per cycle:
//      src_lane = (l&32)|((l^(l>>1))&31)  (^0x30 when dest j0=1)
//      src reg pre-selected by parity(l); 4 cndmask + 4 ds_bpermute per cycle
//  - U3 on lane qubits decomposed as diag(1,e^{i ph}) * RY(th) * diag(1,e^{i lm})
//  - uniform gate constants precomputed by a tiny prep kernel into d_ws
// R3 FIX: the "purely real state" CRX fast path is valid ONLY for the first
//  CRX gate of layer 0. After CRX(0,1), lanes with qubit0=1 are complex, so
//  gates (2,3),(4,5) must use the general form. (R2 applied the fast path to
//  all three -> absmax 2.7e-2 fail.)

#define NQ 8

template<int CTRL>
__device__ __forceinline__ float dppf(float v) {
    return __int_as_float(__builtin_amdgcn_mov_dpp(__float_as_int(v), CTRL, 0xF, 0xF, true));
}

template<int M>
__device__ __forceinline__ float sx(float v) {
    if constexpr (M == 1)       return dppf<0xB1>(v);                 // quad_perm [1,0,3,2]
    else if constexpr (M == 2)  return dppf<0x4E>(v);                 // quad_perm [2,3,0,1]
    else if constexpr (M == 4)  return __int_as_float(__builtin_amdgcn_ds_swizzle(__float_as_int(v), 0x101F)); // xor4
    else if constexpr (M == 8)  return dppf<0x128>(v);                // row_ror:8 = xor8
    else if constexpr (M == 16) return __int_as_float(__builtin_amdgcn_ds_swizzle(__float_as_int(v), 0x401F)); // xor16
    else                        return __shfl_xor(v, 32, 64);         // cross-half
}

__device__ __forceinline__ float bperm(int byte_addr, float v) {
    return __int_as_float(__builtin_amdgcn_ds_bpermute(byte_addr, __float_as_int(v)));
}

#define RY_L(q, M) do { \
    const float tq = ((l >> (5-(q))) & 1) ? s[(q)] : -s[(q)]; \
    const float cq = c[(q)]; \
    float o0 = sx<M>(a0), o1 = sx<M>(a1), o2 = sx<M>(a2), o3 = sx<M>(a3); \
    a0 = fmaf(cq, a0, tq*o0); a1 = fmaf(cq, a1, tq*o1); \
    a2 = fmaf(cq, a2, tq*o2); a3 = fmaf(cq, a3, tq*o3); \
} while(0)

// fused CNOT ring; pb/ba0/ba1 hoisted per-lane constants
#define CNOT_FUSED() do { \
    float t0 = pb ? a2 : a0, t1 = pb ? a3 : a1, t2 = pb ? a1 : a3, t3 = pb ? a0 : a2; \
    a0 = bperm(ba0, t0); a2 = bperm(ba0, t2); \
    a1 = bperm(ba1, t1); a3 = bperm(ba1, t3); \
} while(0)

#define SHFL8(M) \
    float ro0=sx<M>(re0), io0=sx<M>(im0), ro1=sx<M>(re1), io1=sx<M>(im1), \
          ro2=sx<M>(re2), io2=sx<M>(im2), ro3=sx<M>(re3), io3=sx<M>(im3);

#define CRX_LL(CSH, M, cc, sn) do { \
    const bool ct = (l >> (CSH)) & 1; \
    SHFL8(M) \
    if (ct) { \
        re0 = cc*re0 + sn*io0; im0 = cc*im0 - sn*ro0; \
        re1 = cc*re1 + sn*io1; im1 = cc*im1 - sn*ro1; \
        re2 = cc*re2 + sn*io2; im2 = cc*im2 - sn*ro2; \
        re3 = cc*re3 + sn*io3; im3 = cc*im3 - sn*ro3; \
    } \
} while(0)

// CRX fast path: valid ONLY when the ENTIRE incoming state is purely real
// (i.e. only for the very first CRX of layer 0).
#define CRX_FIRST_LL(CSH, M, cc, sn) do { \
    const bool ct = (l >> (CSH)) & 1; \
    float ro0 = sx<M>(re0), ro1 = sx<M>(re1), ro2 = sx<M>(re2), ro3 = sx<M>(re3); \
    if (ct) { \
        im0 = -sn*ro0; re0 = cc*re0; \
        im1 = -sn*ro1; re1 = cc*re1; \
        im2 = -sn*ro2; re2 = cc*re2; \
        im3 = -sn*ro3; re3 = cc*re3; \
    } \
} while(0)

// U3 on lane qubit, decomposed D2(ph) * RY(th) * D1(lm)
#define U3D_LANE(SH, M, UCT, UST, CL, SL, CP, SP) do { \
    const bool b = (l >> (SH)) & 1; \
    if (b) { \
        float r; \
        r = CL*re0 - SL*im0; im0 = CL*im0 + SL*re0; re0 = r; \
        r = CL*re1 - SL*im1; im1 = CL*im1 + SL*re1; re1 = r; \
        r = CL*re2 - SL*im2; im2 = CL*im2 + SL*re2; re2 = r; \
        r = CL*re3 - SL*im3; im3 = CL*im3 + SL*re3; re3 = r; \
    } \
    { \
        const float t = b ? (UST) : -(UST); \
        SHFL8(M) \
        re0 = fmaf(UCT, re0, t*ro0); im0 = fmaf(UCT, im0, t*io0); \
        re1 = fmaf(UCT, re1, t*ro1); im1 = fmaf(UCT, im1, t*io1); \
        re2 = fmaf(UCT, re2, t*ro2); im2 = fmaf(UCT, im2, t*io2); \
        re3 = fmaf(UCT, re3, t*ro3); im3 = fmaf(UCT, im3, t*io3); \
    } \
    if (b) { \
        float r; \
        r = CP*re0 - SP*im0; im0 = CP*im0 + SP*re0; re0 = r; \
        r = CP*re1 - SP*im1; im1 = CP*im1 + SP*re1; re1 = r; \
        r = CP*re2 - SP*im2; im2 = CP*im2 + SP*re2; re2 = r; \
        r = CP*re3 - SP*im3; im3 = CP*im3 + SP*re3; re3 = r; \
    } \
} while(0)

// U3 on qubit 7 (j bit0): direct 2x2 complex, pairs (0,1),(2,3)
#define U3_Q7(CTR, M01R, M01I, M10R, M10I, M11R, M11I) do { \
    float nr0 = CTR*re0 + M01R*re1 - M01I*im1; \
    float ni0 = CTR*im0 + M01R*im1 + M01I*re1; \
    float nr1 = M10R*re0 - M10I*im0 + M11R*re1 - M11I*im1; \
    float ni1 = M10R*im0 + M10I*re0 + M11R*im1 + M11I*re1; \
    float nr2 = CTR*re2 + M01R*re3 - M01I*im3; \
    float ni2 = CTR*im2 + M01R*im3 + M01I*re3; \
    float nr3 = M10R*re2 - M10I*im2 + M11R*re3 - M11I*im3; \
    float ni3 = M10R*im2 + M10I*re2 + M11R*im3 + M11I*re3; \
    re0 = nr0; im0 = ni0; re1 = nr1; im1 = ni1; \
    re2 = nr2; im2 = ni2; re3 = nr3; im3 = ni3; \
} while(0)

// ---- prep kernel: uniform gate constants -> ws[0..27] ----
__global__ void qcnn_prep(const float* __restrict__ crx,
                          const float* __restrict__ u3p,
                          float* __restrict__ ws) {
    if (threadIdx.x == 0 && blockIdx.x == 0) {
#pragma unroll
        for (int L = 0; L < 2; ++L) {
            float sc, cc;
            __sincosf(0.5f * crx[L], &sc, &cc);
            ws[L * 2 + 0] = cc; ws[L * 2 + 1] = sc;
            float th = u3p[3 * L], ph = u3p[3 * L + 1], lm = u3p[3 * L + 2];
            float st_, ct_, sl, cl, sp, cp, spl, cpl;
            __sincosf(0.5f * th, &st_, &ct_);
            __sincosf(lm, &sl, &cl);
            __sincosf(ph, &sp, &cp);
            __sincosf(ph + lm, &spl, &cpl);
            float* p = ws + 4 + L * 12;
            p[0] = ct_;  p[1] = st_;  p[2] = cl;  p[3] = sl;  p[4] = cp;  p[5] = sp;
            p[6] = -st_ * cl;  p[7] = -st_ * sl;   // u01
            p[8] =  st_ * cp;  p[9] =  st_ * sp;   // u10
            p[10] = ct_ * cpl; p[11] = ct_ * spl;  // u11
        }
    }
}

__global__ __launch_bounds__(256) void qcnn_kernel(
    const float* __restrict__ x,
    const float* __restrict__ ws,
    const float* __restrict__ w1,
    const float* __restrict__ b1,
    const float* __restrict__ w2,
    const float* __restrict__ b2,
    float* __restrict__ out,
    int Btot)
{
    const int gtid = blockIdx.x * blockDim.x + threadIdx.x;
    const int wave = gtid >> 6;
    const int l = threadIdx.x & 63;
    if (wave >= Btot) return;

    // hoisted per-lane constants for fused CNOT
    const bool pb = __builtin_popcount(l) & 1;
    const int addr0 = (l & 32) | ((l ^ (l >> 1)) & 31);
    const int ba0 = addr0 << 2;
    const int ba1 = ba0 ^ (48 << 2);

    // per-element RY coefficients
    const float4* xv = (const float4*)(x + wave * NQ);
    float4 xa = xv[0], xb = xv[1];
    float c[NQ], s[NQ];
    {
        float ang[NQ] = {xa.x, xa.y, xa.z, xa.w, xb.x, xb.y, xb.z, xb.w};
#pragma unroll
        for (int q = 0; q < NQ; ++q) __sincosf(0.5f * ang[q], &s[q], &c[q]);
    }

    // uniform constants (scalar loads from ws)
    const float crc0 = ws[0], crs0 = ws[1], crc1 = ws[2], crs1 = ws[3];
    const float uct0 = ws[4],  ust0 = ws[5],  cl0 = ws[6],  sl0 = ws[7],  cp0 = ws[8],  sp0 = ws[9];
    const float u01r0 = ws[10], u01i0 = ws[11], u10r0 = ws[12], u10i0 = ws[13], u11r0 = ws[14], u11i0 = ws[15];
    const float uct1 = ws[16], ust1 = ws[17], cl1 = ws[18], sl1 = ws[19], cp1 = ws[20], sp1 = ws[21];
    const float u01r1 = ws[22], u01i1 = ws[23], u10r1 = ws[24], u10i1 = ws[25], u11r1 = ws[26], u11i1 = ws[27];

    // ================= Phase 1 =================
    // cycle-1 RY analytically: amp(i) = prod_q (bit_q(i) ? s_q : c_q)
    float a0, a1, a2, a3;
    {
        float pl = (((l >> 5) & 1) ? s[0] : c[0]);
        pl *= (((l >> 4) & 1) ? s[1] : c[1]);
        pl *= (((l >> 3) & 1) ? s[2] : c[2]);
        pl *= (((l >> 2) & 1) ? s[3] : c[3]);
        pl *= (((l >> 1) & 1) ? s[4] : c[4]);
        pl *= ((l & 1) ? s[5] : c[5]);
        float pc6 = pl * c[6], ps6 = pl * s[6];
        a0 = pc6 * c[7]; a1 = pc6 * s[7];
        a2 = ps6 * c[7]; a3 = ps6 * s[7];
    }
    CNOT_FUSED();
#pragma unroll
    for (int cyc = 0; cyc < 3; ++cyc) {
        RY_L(0, 32); RY_L(1, 16); RY_L(2, 8); RY_L(3, 4); RY_L(4, 2); RY_L(5, 1);
        { // RY q=6: pairs (a0,a2),(a1,a3)
            float n0 = c[6]*a0 - s[6]*a2, n1 = c[6]*a1 - s[6]*a3;
            float n2 = s[6]*a0 + c[6]*a2, n3 = s[6]*a1 + c[6]*a3;
            a0 = n0; a1 = n1; a2 = n2; a3 = n3;
        }
        { // RY q=7: pairs (a0,a1),(a2,a3)
            float n0 = c[7]*a0 - s[7]*a1, n1 = s[7]*a0 + c[7]*a1;
            float n2 = c[7]*a2 - s[7]*a3, n3 = s[7]*a2 + c[7]*a3;
            a0 = n0; a1 = n1; a2 = n2; a3 = n3;
        }
        CNOT_FUSED();
    }

    // ================= Phase 2: complex =================
    float re0 = a0, re1 = a1, re2 = a2, re3 = a3;
    float im0 = 0.f, im1 = 0.f, im2 = 0.f, im3 = 0.f;

    // Layer 0, first sublayer: (0,1),(2,3),(4,5),(6,7)
    CRX_FIRST_LL(5, 16, crc0, crs0);   // (0,1): state still fully real here
    CRX_LL(3, 4,  crc0, crs0);         // (2,3): general (im nonzero on q0=1 lanes)
    CRX_LL(1, 1,  crc0, crs0);         // (4,5): general
    { // (6,7): control j1 (regs 2,3), target j0 — in-register pair (2,3)
        float nr2 = crc0*re2 + crs0*im3, ni2 = crc0*im2 - crs0*re3;
        float nr3 = crc0*re3 + crs0*im2, ni3 = crc0*im3 - crs0*re2;
        re2 = nr2; im2 = ni2; re3 = nr3; im3 = ni3;
    }
    // second sublayer: (1,2),(3,4),(5,6)
    CRX_LL(4, 8, crc0, crs0);
    CRX_LL(2, 2, crc0, crs0);
    { // (5,6): control lane bit0, target j bit1: pairs (0,2),(1,3)
        if (l & 1) {
            float nr0 = crc0*re0 + crs0*im2, ni0 = crc0*im0 - crs0*re2;
            float nr2 = crc0*re2 + crs0*im0, ni2 = crc0*im2 - crs0*re0;
            float nr1 = crc0*re1 + crs0*im3, ni1 = crc0*im1 - crs0*re3;
            float nr3 = crc0*re3 + crs0*im1, ni3 = crc0*im3 - crs0*re1;
            re0 = nr0; im0 = ni0; re1 = nr1; im1 = ni1;
            re2 = nr2; im2 = ni2; re3 = nr3; im3 = ni3;
        }
    }
    // U3 on 1,3,5 (decomposed), 7 (direct)
    U3D_LANE(4, 16, uct0, ust0, cl0, sl0, cp0, sp0); // q=1
    U3D_LANE(2, 4,  uct0, ust0, cl0, sl0, cp0, sp0); // q=3
    U3D_LANE(0, 1,  uct0, ust0, cl0, sl0, cp0, sp0); // q=5
    U3_Q7(uct0, u01r0, u01i0, u10r0, u10i0, u11r0, u11i0);

    // Layer 1: CRX (1,3),(5,7) then (3,5); U3 on 3,7
    CRX_LL(4, 4, crc1, crs1);      // (1,3)
    { // (5,7): control lane bit0, target j bit0: pairs (0,1),(2,3)
        if (l & 1) {
            float nr0 = crc1*re0 + crs1*im1, ni0 = crc1*im0 - crs1*re1;
            float nr1 = crc1*re1 + crs1*im0, ni1 = crc1*im1 - crs1*re0;
            float nr2 = crc1*re2 + crs1*im3, ni2 = crc1*im2 - crs1*re3;
            float nr3 = crc1*re3 + crs1*im2, ni3 = crc1*im3 - crs1*re2;
            re0 = nr0; im0 = ni0; re1 = nr1; im1 = ni1;
            re2 = nr2; im2 = ni2; re3 = nr3; im3 = ni3;
        }
    }
    CRX_LL(2, 1, crc1, crs1);      // (3,5)
    U3D_LANE(2, 4, uct1, ust1, cl1, sl1, cp1, sp1); // q=3
    U3_Q7(uct1, u01r1, u01i1, u10r1, u10i1, u11r1, u11i1);

    // ================= expvals + MLP =================
    float n0 = re0*re0 + im0*im0;
    float n1 = re1*re1 + im1*im1;
    float n2 = re2*re2 + im2*im2;
    float n3 = re3*re3 + im3*im3;
    float f0 = (((l >> 2) & 1) ? -1.0f : 1.0f) * (n0 + n1 + n2 + n3); // Z(q3): lane bit2
    float f1 = (n0 - n1) + (n2 - n3);                                 // Z(q7): j bit0
    f0 += sx<1>(f0);  f1 += sx<1>(f1);
    f0 += sx<2>(f0);  f1 += sx<2>(f1);
    f0 += sx<4>(f0);  f1 += sx<4>(f1);
    f0 += sx<8>(f0);  f1 += sx<8>(f1);
    f0 += sx<16>(f0); f1 += sx<16>(f1);
    f0 += sx<32>(f0); f1 += sx<32>(f1);

    // MLP: 10 hidden units on lanes 0..9 of each 16-lane row
    const int k = l & 15;
    float contrib = 0.0f;
    if (k < 10) {
        float z = fmaf(f0, w1[k], fmaf(f1, w1[10 + k], b1[k]));
        float e = __expf(2.0f * z);
        float h = (e - 1.0f) / (e + 1.0f);
        contrib = h * w2[k];
    }
    contrib += sx<1>(contrib);
    contrib += sx<2>(contrib);
    contrib += sx<4>(contrib);
    contrib += sx<8>(contrib);
    if (l == 0) {
        float a = contrib + b2[0];
        out[wave] = 1.0f / (1.0f + __expf(-a));
    }
}

extern "C" void kernel_launch(void* const* d_in, const int* in_sizes, int n_in,
                              void* d_out, int out_size, void* d_ws, size_t ws_size,
                              hipStream_t stream) {
    const float* x   = (const float*)d_in[0];
    const float* crx = (const float*)d_in[1];
    const float* u3p = (const float*)d_in[2];
    const float* w1  = (const float*)d_in[3];
    const float* b1  = (const float*)d_in[4];
    const float* w2  = (const float*)d_in[5];
    const float* b2  = (const float*)d_in[6];
    float* out = (float*)d_out;
    float* ws  = (float*)d_ws;

    const int B = in_sizes[0] / NQ;          // 65536
    hipLaunchKernelGGL(qcnn_prep, dim3(1), dim3(64), 0, stream, crx, u3p, ws);
    const int wavesPerBlock = 256 / 64;
    const int grid = (B + wavesPerBlock - 1) / wavesPerBlock;
    hipLaunchKernelGGL(qcnn_kernel, dim3(grid), dim3(256), 0, stream,
                       x, ws, w1, b1, w2, b2, out, B);
}

// Round 5
// 141.963 us; speedup vs baseline: 1.7642x; 1.0761x over previous
//
#include <hip/hip_runtime.h>

// QCNN: 8 qubits, 256 amplitudes, one wave per batch element.
// Lane l holds amplitudes i = (l<<2)|j, j=0..3. Qubit q <-> bit (7-q) of i:
// q=0..5 -> lane bits 5..0, q=6 -> j bit1, q=7 -> j bit0.
//
// R5 changes (still VALU-issue-bound at 91%):
//  - ALL xor-shuffles (masks 1..16) now ds_swizzle (DS pipe, ~4x headroom)
//    instead of DPP v_mov (VALU pipe). xor32 stays __shfl_xor (bpermute).
//  - Layer-0 U3s on q1,q3,q5,q7 commute -> fused as [prod D2][prod RY][prod D1];
//    combined diagonal = phase angle*(k + j0), k = b4+b2+b0 (lane-constant),
//    computed with 4 __sincosf (trans pipe) + two 16-op DIAG4 applies.
//  - RY sign-selects hoisted out of all loops (ts[q], tu1/tu3/tu5).

#define NQ 8

template<int M>
__device__ __forceinline__ float sx(float v) {
    if constexpr (M == 32) return __shfl_xor(v, 32, 64);                // cross-half bpermute
    else return __int_as_float(__builtin_amdgcn_ds_swizzle(
                 __float_as_int(v), (M << 10) | 0x1F));                 // BitMode xor
}

__device__ __forceinline__ float bperm(int byte_addr, float v) {
    return __int_as_float(__builtin_amdgcn_ds_bpermute(byte_addr, __float_as_int(v)));
}

#define RY_L(q, M) do { \
    float o0 = sx<M>(a0), o1 = sx<M>(a1), o2 = sx<M>(a2), o3 = sx<M>(a3); \
    a0 = fmaf(c[q], a0, ts[q]*o0); a1 = fmaf(c[q], a1, ts[q]*o1); \
    a2 = fmaf(c[q], a2, ts[q]*o2); a3 = fmaf(c[q], a3, ts[q]*o3); \
} while(0)

// fused CNOT ring; pb/ba0/ba1 hoisted per-lane constants
#define CNOT_FUSED() do { \
    float t0 = pb ? a2 : a0, t1 = pb ? a3 : a1, t2 = pb ? a1 : a3, t3 = pb ? a0 : a2; \
    a0 = bperm(ba0, t0); a2 = bperm(ba0, t2); \
    a1 = bperm(ba1, t1); a3 = bperm(ba1, t3); \
} while(0)

#define SHFL8(M) \
    float ro0=sx<M>(re0), io0=sx<M>(im0), ro1=sx<M>(re1), io1=sx<M>(im1), \
          ro2=sx<M>(re2), io2=sx<M>(im2), ro3=sx<M>(re3), io3=sx<M>(im3);

#define CRX_LL(CSH, M, cc, sn) do { \
    const bool ct = (l >> (CSH)) & 1; \
    SHFL8(M) \
    if (ct) { \
        re0 = cc*re0 + sn*io0; im0 = cc*im0 - sn*ro0; \
        re1 = cc*re1 + sn*io1; im1 = cc*im1 - sn*ro1; \
        re2 = cc*re2 + sn*io2; im2 = cc*im2 - sn*ro2; \
        re3 = cc*re3 + sn*io3; im3 = cc*im3 - sn*ro3; \
    } \
} while(0)

// CRX fast path: valid ONLY when the ENTIRE incoming state is purely real.
#define CRX_FIRST_LL(CSH, M, cc, sn) do { \
    const bool ct = (l >> (CSH)) & 1; \
    float ro0 = sx<M>(re0), ro1 = sx<M>(re1), ro2 = sx<M>(re2), ro3 = sx<M>(re3); \
    if (ct) { \
        im0 = -sn*ro0; re0 = cc*re0; \
        im1 = -sn*ro1; re1 = cc*re1; \
        im2 = -sn*ro2; re2 = cc*re2; \
        im3 = -sn*ro3; re3 = cc*re3; \
    } \
} while(0)

// complex RY(th0) on a lane qubit (uniform angle, per-lane sign T hoisted)
#define RYC0(M, T) do { \
    SHFL8(M) \
    re0 = fmaf(uct0, re0, (T)*ro0); im0 = fmaf(uct0, im0, (T)*io0); \
    re1 = fmaf(uct0, re1, (T)*ro1); im1 = fmaf(uct0, im1, (T)*io1); \
    re2 = fmaf(uct0, re2, (T)*ro2); im2 = fmaf(uct0, im2, (T)*io2); \
    re3 = fmaf(uct0, re3, (T)*ro3); im3 = fmaf(uct0, im3, (T)*io3); \
} while(0)

// multiply regs 0,2 by (CA,SA) and regs 1,3 by (CB,SB)  [complex phase]
#define DIAG4(CA, SA, CB, SB) do { float r_; \
    r_ = (CA)*re0 - (SA)*im0; im0 = fmaf((CA), im0, (SA)*re0); re0 = r_; \
    r_ = (CB)*re1 - (SB)*im1; im1 = fmaf((CB), im1, (SB)*re1); re1 = r_; \
    r_ = (CA)*re2 - (SA)*im2; im2 = fmaf((CA), im2, (SA)*re2); re2 = r_; \
    r_ = (CB)*re3 - (SB)*im3; im3 = fmaf((CB), im3, (SB)*re3); re3 = r_; \
} while(0)

// U3 on lane qubit, decomposed D2(ph) * RY(th) * D1(lm)  (layer 1 only)
#define U3D_LANE(SH, M, UCT, UST, CL, SL, CP, SP) do { \
    const bool b = (l >> (SH)) & 1; \
    if (b) { \
        float r; \
        r = CL*re0 - SL*im0; im0 = CL*im0 + SL*re0; re0 = r; \
        r = CL*re1 - SL*im1; im1 = CL*im1 + SL*re1; re1 = r; \
        r = CL*re2 - SL*im2; im2 = CL*im2 + SL*re2; re2 = r; \
        r = CL*re3 - SL*im3; im3 = CL*im3 + SL*re3; re3 = r; \
    } \
    { \
        const float t = b ? (UST) : -(UST); \
        SHFL8(M) \
        re0 = fmaf(UCT, re0, t*ro0); im0 = fmaf(UCT, im0, t*io0); \
        re1 = fmaf(UCT, re1, t*ro1); im1 = fmaf(UCT, im1, t*io1); \
        re2 = fmaf(UCT, re2, t*ro2); im2 = fmaf(UCT, im2, t*io2); \
        re3 = fmaf(UCT, re3, t*ro3); im3 = fmaf(UCT, im3, t*io3); \
    } \
    if (b) { \
        float r; \
        r = CP*re0 - SP*im0; im0 = CP*im0 + SP*re0; re0 = r; \
        r = CP*re1 - SP*im1; im1 = CP*im1 + SP*re1; re1 = r; \
        r = CP*re2 - SP*im2; im2 = CP*im2 + SP*re2; re2 = r; \
        r = CP*re3 - SP*im3; im3 = CP*im3 + SP*re3; re3 = r; \
    } \
} while(0)

// U3 on qubit 7 (j bit0): direct 2x2 complex, pairs (0,1),(2,3)  (layer 1 only)
#define U3_Q7(CTR, M01R, M01I, M10R, M10I, M11R, M11I) do { \
    float nr0 = CTR*re0 + M01R*re1 - M01I*im1; \
    float ni0 = CTR*im0 + M01R*im1 + M01I*re1; \
    float nr1 = M10R*re0 - M10I*im0 + M11R*re1 - M11I*im1; \
    float ni1 = M10R*im0 + M10I*re0 + M11R*im1 + M11I*re1; \
    float nr2 = CTR*re2 + M01R*re3 - M01I*im3; \
    float ni2 = CTR*im2 + M01R*im3 + M01I*re3; \
    float nr3 = M10R*re2 - M10I*im2 + M11R*re3 - M11I*im3; \
    float ni3 = M10R*im2 + M10I*re2 + M11R*im3 + M11I*re3; \
    re0 = nr0; im0 = ni0; re1 = nr1; im1 = ni1; \
    re2 = nr2; im2 = ni2; re3 = nr3; im3 = ni3; \
} while(0)

// ---- prep kernel: uniform gate constants -> ws ----
// ws[0..3]  crc0, crs0, crc1, crs1
// ws[4..7]  uct0, ust0, lm0, ph0           (layer-0 U3, fused-diag form)
// ws[8..13] uct1, ust1, cl1, sl1, cp1, sp1 (layer-1 U3 decomposed)
// ws[14..19] u01r1, u01i1, u10r1, u10i1, u11r1, u11i1 (layer-1 U3_Q7 direct)
__global__ void qcnn_prep(const float* __restrict__ crx,
                          const float* __restrict__ u3p,
                          float* __restrict__ ws) {
    if (threadIdx.x == 0 && blockIdx.x == 0) {
        float sc0, cc0, sc1, cc1;
        __sincosf(0.5f * crx[0], &sc0, &cc0);
        __sincosf(0.5f * crx[1], &sc1, &cc1);
        ws[0] = cc0; ws[1] = sc0; ws[2] = cc1; ws[3] = sc1;
        // layer 0
        {
            float th = u3p[0], ph = u3p[1], lm = u3p[2];
            float st_, ct_;
            __sincosf(0.5f * th, &st_, &ct_);
            ws[4] = ct_; ws[5] = st_; ws[6] = lm; ws[7] = ph;
        }
        // layer 1
        {
            float th = u3p[3], ph = u3p[4], lm = u3p[5];
            float st_, ct_, sl, cl, sp, cp, spl, cpl;
            __sincosf(0.5f * th, &st_, &ct_);
            __sincosf(lm, &sl, &cl);
            __sincosf(ph, &sp, &cp);
            __sincosf(ph + lm, &spl, &cpl);
            ws[8] = ct_;  ws[9] = st_;  ws[10] = cl; ws[11] = sl; ws[12] = cp; ws[13] = sp;
            ws[14] = -st_ * cl;  ws[15] = -st_ * sl;   // u01
            ws[16] =  st_ * cp;  ws[17] =  st_ * sp;   // u10
            ws[18] =  ct_ * cpl; ws[19] =  ct_ * spl;  // u11
        }
    }
}

__global__ __launch_bounds__(256) void qcnn_kernel(
    const float* __restrict__ x,
    const float* __restrict__ ws,
    const float* __restrict__ w1,
    const float* __restrict__ b1,
    const float* __restrict__ w2,
    const float* __restrict__ b2,
    float* __restrict__ out,
    int Btot)
{
    const int gtid = blockIdx.x * blockDim.x + threadIdx.x;
    const int wave = gtid >> 6;
    const int l = threadIdx.x & 63;
    if (wave >= Btot) return;

    // hoisted per-lane constants for fused CNOT
    const bool pb = __builtin_popcount(l) & 1;
    const int addr0 = (l & 32) | ((l ^ (l >> 1)) & 31);
    const int ba0 = addr0 << 2;
    const int ba1 = ba0 ^ (48 << 2);

    // per-element RY coefficients + hoisted per-lane signed sines
    const float4* xv = (const float4*)(x + wave * NQ);
    float4 xa = xv[0], xb = xv[1];
    float c[NQ], s[NQ], ts[6];
    {
        float ang[NQ] = {xa.x, xa.y, xa.z, xa.w, xb.x, xb.y, xb.z, xb.w};
#pragma unroll
        for (int q = 0; q < NQ; ++q) __sincosf(0.5f * ang[q], &s[q], &c[q]);
#pragma unroll
        for (int q = 0; q < 6; ++q) ts[q] = ((l >> (5 - q)) & 1) ? s[q] : -s[q];
    }

    // uniform constants
    const float crc0 = ws[0], crs0 = ws[1], crc1 = ws[2], crs1 = ws[3];
    const float uct0 = ws[4], ust0 = ws[5], lm0 = ws[6], ph0 = ws[7];
    const float uct1 = ws[8],  ust1 = ws[9],  cl1 = ws[10], sl1 = ws[11], cp1 = ws[12], sp1 = ws[13];
    const float u01r1 = ws[14], u01i1 = ws[15], u10r1 = ws[16], u10i1 = ws[17], u11r1 = ws[18], u11i1 = ws[19];

    // fused layer-0 U3 diagonal phases: k = b4+b2+b0; regs 0,2 get angle*k,
    // regs 1,3 get angle*(k+1)  (trans-pipe sincos, hoisted early)
    const float kf = (float)(((l >> 4) & 1) + ((l >> 2) & 1) + (l & 1));
    float sA0, cA0, sB0, cB0, sA1, cA1, sB1, cB1;
    __sincosf(kf * lm0,          &sA0, &cA0);
    __sincosf((kf + 1.f) * lm0,  &sB0, &cB0);
    __sincosf(kf * ph0,          &sA1, &cA1);
    __sincosf((kf + 1.f) * ph0,  &sB1, &cB1);
    const float tu1 = ((l >> 4) & 1) ? ust0 : -ust0;
    const float tu3 = ((l >> 2) & 1) ? ust0 : -ust0;
    const float tu5 = (l & 1)        ? ust0 : -ust0;

    // ================= Phase 1 =================
    // cycle-1 RY analytically: amp(i) = prod_q (bit_q(i) ? s_q : c_q)
    float a0, a1, a2, a3;
    {
        float pl = (((l >> 5) & 1) ? s[0] : c[0]);
        pl *= (((l >> 4) & 1) ? s[1] : c[1]);
        pl *= (((l >> 3) & 1) ? s[2] : c[2]);
        pl *= (((l >> 2) & 1) ? s[3] : c[3]);
        pl *= (((l >> 1) & 1) ? s[4] : c[4]);
        pl *= ((l & 1) ? s[5] : c[5]);
        float pc6 = pl * c[6], ps6 = pl * s[6];
        a0 = pc6 * c[7]; a1 = pc6 * s[7];
        a2 = ps6 * c[7]; a3 = ps6 * s[7];
    }
    CNOT_FUSED();
#pragma unroll
    for (int cyc = 0; cyc < 3; ++cyc) {
        RY_L(0, 32); RY_L(1, 16); RY_L(2, 8); RY_L(3, 4); RY_L(4, 2); RY_L(5, 1);
        { // RY q=6: pairs (a0,a2),(a1,a3)
            float n0 = c[6]*a0 - s[6]*a2, n1 = c[6]*a1 - s[6]*a3;
            float n2 = s[6]*a0 + c[6]*a2, n3 = s[6]*a1 + c[6]*a3;
            a0 = n0; a1 = n1; a2 = n2; a3 = n3;
        }
        { // RY q=7: pairs (a0,a1),(a2,a3)
            float n0 = c[7]*a0 - s[7]*a1, n1 = s[7]*a0 + c[7]*a1;
            float n2 = c[7]*a2 - s[7]*a3, n3 = s[7]*a2 + c[7]*a3;
            a0 = n0; a1 = n1; a2 = n2; a3 = n3;
        }
        CNOT_FUSED();
    }

    // ================= Phase 2: complex =================
    float re0 = a0, re1 = a1, re2 = a2, re3 = a3;
    float im0 = 0.f, im1 = 0.f, im2 = 0.f, im3 = 0.f;

    // Layer 0, first sublayer: (0,1),(2,3),(4,5),(6,7)
    CRX_FIRST_LL(5, 16, crc0, crs0);   // (0,1): state still fully real here
    CRX_LL(3, 4,  crc0, crs0);         // (2,3)
    CRX_LL(1, 1,  crc0, crs0);         // (4,5)
    { // (6,7): control j1 (regs 2,3), target j0 — in-register pair (2,3)
        float nr2 = crc0*re2 + crs0*im3, ni2 = crc0*im2 - crs0*re3;
        float nr3 = crc0*re3 + crs0*im2, ni3 = crc0*im3 - crs0*re2;
        re2 = nr2; im2 = ni2; re3 = nr3; im3 = ni3;
    }
    // second sublayer: (1,2),(3,4),(5,6)
    CRX_LL(4, 8, crc0, crs0);
    CRX_LL(2, 2, crc0, crs0);
    { // (5,6): control lane bit0, target j bit1: pairs (0,2),(1,3)
        if (l & 1) {
            float nr0 = crc0*re0 + crs0*im2, ni0 = crc0*im0 - crs0*re2;
            float nr2 = crc0*re2 + crs0*im0, ni2 = crc0*im2 - crs0*re0;
            float nr1 = crc0*re1 + crs0*im3, ni1 = crc0*im1 - crs0*re3;
            float nr3 = crc0*re3 + crs0*im1, ni3 = crc0*im3 - crs0*re1;
            re0 = nr0; im0 = ni0; re1 = nr1; im1 = ni1;
            re2 = nr2; im2 = ni2; re3 = nr3; im3 = ni3;
        }
    }
    // ---- fused layer-0 U3 on q1,q3,q5,q7: [D2][RY x4][D1] (commuting qubits) ----
    DIAG4(cA0, sA0, cB0, sB0);         // prod D1 = phase lm0*(k + j0)
    RYC0(16, tu1);                     // RY(th0) q=1
    RYC0(4,  tu3);                     // RY(th0) q=3
    RYC0(1,  tu5);                     // RY(th0) q=5
    { // RY(th0) q=7: in-register pairs (0,1),(2,3), real coefficients
        float nr0 = uct0*re0 - ust0*re1, ni0 = uct0*im0 - ust0*im1;
        float nr1 = ust0*re0 + uct0*re1, ni1 = ust0*im0 + uct0*im1;
        float nr2 = uct0*re2 - ust0*re3, ni2 = uct0*im2 - ust0*im3;
        float nr3 = ust0*re2 + uct0*re3, ni3 = ust0*im2 + uct0*im3;
        re0 = nr0; im0 = ni0; re1 = nr1; im1 = ni1;
        re2 = nr2; im2 = ni2; re3 = nr3; im3 = ni3;
    }
    DIAG4(cA1, sA1, cB1, sB1);         // prod D2 = phase ph0*(k + j0)

    // Layer 1: CRX (1,3),(5,7) then (3,5); U3 on 3,7
    CRX_LL(4, 4, crc1, crs1);      // (1,3)
    { // (5,7): control lane bit0, target j bit0: pairs (0,1),(2,3)
        if (l & 1) {
            float nr0 = crc1*re0 + crs1*im1, ni0 = crc1*im0 - crs1*re1;
            float nr1 = crc1*re1 + crs1*im0, ni1 = crc1*im1 - crs1*re0;
            float nr2 = crc1*re2 + crs1*im3, ni2 = crc1*im2 - crs1*re3;
            float nr3 = crc1*re3 + crs1*im2, ni3 = crc1*im3 - crs1*re2;
            re0 = nr0; im0 = ni0; re1 = nr1; im1 = ni1;
            re2 = nr2; im2 = ni2; re3 = nr3; im3 = ni3;
        }
    }
    CRX_LL(2, 1, crc1, crs1);      // (3,5)
    U3D_LANE(2, 4, uct1, ust1, cl1, sl1, cp1, sp1); // q=3
    U3_Q7(uct1, u01r1, u01i1, u10r1, u10i1, u11r1, u11i1);

    // ================= expvals + MLP =================
    float n0 = re0*re0 + im0*im0;
    float n1 = re1*re1 + im1*im1;
    float n2 = re2*re2 + im2*im2;
    float n3 = re3*re3 + im3*im3;
    float f0 = (((l >> 2) & 1) ? -1.0f : 1.0f) * (n0 + n1 + n2 + n3); // Z(q3): lane bit2
    float f1 = (n0 - n1) + (n2 - n3);                                 // Z(q7): j bit0
    f0 += sx<1>(f0);  f1 += sx<1>(f1);
    f0 += sx<2>(f0);  f1 += sx<2>(f1);
    f0 += sx<4>(f0);  f1 += sx<4>(f1);
    f0 += sx<8>(f0);  f1 += sx<8>(f1);
    f0 += sx<16>(f0); f1 += sx<16>(f1);
    f0 += sx<32>(f0); f1 += sx<32>(f1);

    // MLP: 10 hidden units on lanes 0..9 of each 16-lane row
    const int k = l & 15;
    float contrib = 0.0f;
    if (k < 10) {
        float z = fmaf(f0, w1[k], fmaf(f1, w1[10 + k], b1[k]));
        float e = __expf(2.0f * z);
        float h = (e - 1.0f) / (e + 1.0f);
        contrib = h * w2[k];
    }
    contrib += sx<1>(contrib);
    contrib += sx<2>(contrib);
    contrib += sx<4>(contrib);
    contrib += sx<8>(contrib);
    if (l == 0) {
        float a = contrib + b2[0];
        out[wave] = 1.0f / (1.0f + __expf(-a));
    }
}

extern "C" void kernel_launch(void* const* d_in, const int* in_sizes, int n_in,
                              void* d_out, int out_size, void* d_ws, size_t ws_size,
                              hipStream_t stream) {
    const float* x   = (const float*)d_in[0];
    const float* crx = (const float*)d_in[1];
    const float* u3p = (const float*)d_in[2];
    const float* w1  = (const float*)d_in[3];
    const float* b1  = (const float*)d_in[4];
    const float* w2  = (const float*)d_in[5];
    const float* b2  = (const float*)d_in[6];
    float* out = (float*)d_out;
    float* ws  = (float*)d_ws;

    const int B = in_sizes[0] / NQ;          // 65536
    hipLaunchKernelGGL(qcnn_prep, dim3(1), dim3(64), 0, stream, crx, u3p, ws);
    const int wavesPerBlock = 256 / 64;
    const int grid = (B + wavesPerBlock - 1) / wavesPerBlock;
    hipLaunchKernelGGL(qcnn_kernel, dim3(grid), dim3(256), 0, stream,
                       x, ws, w1, b1, w2, b2, out, B);
}

// Round 6
// 128.550 us; speedup vs baseline: 1.9483x; 1.1043x over previous
//
#include <hip/hip_runtime.h>

// QCNN: 8 qubits, 256 amplitudes, one wave per batch element.
// Lane l holds amplitudes i = (l<<2)|j, j=0..3. Qubit q <-> bit (7-q) of i:
// q=0..5 -> lane bits 5..0, q=6 -> j bit1, q=7 -> j bit0.
//
// R6: VALU-issue-bound at 93% -> pack all gate math as float2 so LLVM emits
// v_pk_fma_f32/v_pk_mul_f32 (VOP3P, 2 fp32/slot on gfx950). State packed as
// like-components over j-pairs: Ra={re0,re1}, Rb={re2,re3}, Ia, Ib.
// Lane-qubit gates -> pure elementwise pk ops; q7 (j bit0) gates -> one
// component swap + pk ops. Layer-0 fused-U3 diagonal phases (k=0..3) are
// table-ized in d_ws by the prep kernel (2 float4 VMEM loads vs 8 trans ops).

#define NQ 8

typedef float v2 __attribute__((ext_vector_type(2)));

__device__ __forceinline__ v2 sp(float x) { return (v2){x, x}; }
__device__ __forceinline__ v2 fma2(v2 a, v2 b, v2 c) { return __builtin_elementwise_fma(a, b, c); }
__device__ __forceinline__ v2 swp(v2 v) { return __builtin_shufflevector(v, v, 1, 0); }

template<int M>
__device__ __forceinline__ float sx(float v) {
    if constexpr (M == 32) return __shfl_xor(v, 32, 64);                // cross-half bpermute
    else return __int_as_float(__builtin_amdgcn_ds_swizzle(
                 __float_as_int(v), (M << 10) | 0x1F));                 // BitMode xor
}
template<int M>
__device__ __forceinline__ v2 sx2(v2 v) {
    v2 r; r.x = sx<M>(v.x); r.y = sx<M>(v.y); return r;
}
__device__ __forceinline__ float bperm(int byte_addr, float v) {
    return __int_as_float(__builtin_amdgcn_ds_bpermute(byte_addr, __float_as_int(v)));
}

// RY on lane qubit q (phase 1, real state A,B)
#define RY_L(q, M) do { \
    v2 oA = sx2<M>(A), oB = sx2<M>(B); \
    A = fma2(sp(c[q]), A, sp(ts[q]) * oA); \
    B = fma2(sp(c[q]), B, sp(ts[q]) * oB); \
} while(0)

// fused CNOT ring (verified R2): TA.x,TA.y,TS.y,TS.x = t0,t1,t2,t3
#define CNOT_FUSED() do { \
    v2 TA = pb ? B : A; \
    v2 TS = pb ? A : B; \
    A = (v2){ bperm(ba0, TA.x), bperm(ba1, TA.y) }; \
    B = (v2){ bperm(ba0, TS.y), bperm(ba1, TS.x) }; \
} while(0)

// general CRX, control on lane bit CSH, target lane qubit via shuffle M
#define CRX_LL(CSH, M, cc, sn) do { \
    const bool ct = (l >> (CSH)) & 1; \
    v2 oRa = sx2<M>(Ra), oIa = sx2<M>(Ia), oRb = sx2<M>(Rb), oIb = sx2<M>(Ib); \
    if (ct) { \
        Ra = fma2(sp(cc), Ra, sp(sn)  * oIa); \
        Ia = fma2(sp(cc), Ia, sp(-(sn)) * oRa); \
        Rb = fma2(sp(cc), Rb, sp(sn)  * oIb); \
        Ib = fma2(sp(cc), Ib, sp(-(sn)) * oRb); \
    } \
} while(0)

// complex RY(th0) on lane qubit (layer-0 fused U3), sign T hoisted
#define RYC0(M, T) do { \
    v2 oRa = sx2<M>(Ra), oIa = sx2<M>(Ia), oRb = sx2<M>(Rb), oIb = sx2<M>(Ib); \
    Ra = fma2(sp(uct0), Ra, sp(T) * oRa); Ia = fma2(sp(uct0), Ia, sp(T) * oIa); \
    Rb = fma2(sp(uct0), Rb, sp(T) * oRb); Ib = fma2(sp(uct0), Ib, sp(T) * oIb); \
} while(0)

// ---- prep kernel: uniform gate constants + layer-0 diag table -> ws ----
// ws[0..3]   crc0, crs0, crc1, crs1
// ws[4..5]   uct0, ust0
// ws[8..13]  uct1, ust1, cl1, sl1, cp1, sp1
// ws[14..19] u01r1, u01i1, u10r1, u10i1, u11r1, u11i1
// ws[20+k*8 ..] k=0..3: cos(k*lm0), sin(k*lm0), cos((k+1)lm0), sin((k+1)lm0),
//                        cos(k*ph0), sin(k*ph0), cos((k+1)ph0), sin((k+1)ph0)
__global__ void qcnn_prep(const float* __restrict__ crx,
                          const float* __restrict__ u3p,
                          float* __restrict__ ws) {
    if (threadIdx.x == 0 && blockIdx.x == 0) {
        float sc0, cc0, sc1, cc1;
        __sincosf(0.5f * crx[0], &sc0, &cc0);
        __sincosf(0.5f * crx[1], &sc1, &cc1);
        ws[0] = cc0; ws[1] = sc0; ws[2] = cc1; ws[3] = sc1;
        // layer 0
        float lm0, ph0;
        {
            float th = u3p[0]; ph0 = u3p[1]; lm0 = u3p[2];
            float st_, ct_;
            __sincosf(0.5f * th, &st_, &ct_);
            ws[4] = ct_; ws[5] = st_;
        }
        // layer 1
        {
            float th = u3p[3], ph = u3p[4], lm = u3p[5];
            float st_, ct_, sl, cl, sp_, cp, spl, cpl;
            __sincosf(0.5f * th, &st_, &ct_);
            __sincosf(lm, &sl, &cl);
            __sincosf(ph, &sp_, &cp);
            __sincosf(ph + lm, &spl, &cpl);
            ws[8] = ct_;  ws[9] = st_;  ws[10] = cl; ws[11] = sl; ws[12] = cp; ws[13] = sp_;
            ws[14] = -st_ * cl;  ws[15] = -st_ * sl;   // u01
            ws[16] =  st_ * cp;  ws[17] =  st_ * sp_;  // u10
            ws[18] =  ct_ * cpl; ws[19] =  ct_ * spl;  // u11
        }
        // layer-0 fused diag table
        for (int k = 0; k < 4; ++k) {
            float kf = (float)k;
            float sA0, cA0, sB0, cB0, sA1, cA1, sB1, cB1;
            __sincosf(kf * lm0,         &sA0, &cA0);
            __sincosf((kf + 1.f) * lm0, &sB0, &cB0);
            __sincosf(kf * ph0,         &sA1, &cA1);
            __sincosf((kf + 1.f) * ph0, &sB1, &cB1);
            float* q = ws + 20 + k * 8;
            q[0] = cA0; q[1] = sA0; q[2] = cB0; q[3] = sB0;
            q[4] = cA1; q[5] = sA1; q[6] = cB1; q[7] = sB1;
        }
    }
}

__global__ __launch_bounds__(256) void qcnn_kernel(
    const float* __restrict__ x,
    const float* __restrict__ ws,
    const float* __restrict__ w1,
    const float* __restrict__ b1,
    const float* __restrict__ w2,
    const float* __restrict__ b2,
    float* __restrict__ out,
    int Btot)
{
    const int gtid = blockIdx.x * blockDim.x + threadIdx.x;
    const int wave = gtid >> 6;
    const int l = threadIdx.x & 63;
    if (wave >= Btot) return;

    // hoisted per-lane constants for fused CNOT
    const bool pb = __builtin_popcount(l) & 1;
    const int addr0 = (l & 32) | ((l ^ (l >> 1)) & 31);
    const int ba0 = addr0 << 2;
    const int ba1 = ba0 ^ (48 << 2);

    // per-element RY coefficients + hoisted per-lane signed sines
    const float4* xv = (const float4*)(x + wave * NQ);
    float4 xa = xv[0], xb = xv[1];
    float c[NQ], s[NQ], ts[6];
    {
        float ang[NQ] = {xa.x, xa.y, xa.z, xa.w, xb.x, xb.y, xb.z, xb.w};
#pragma unroll
        for (int q = 0; q < NQ; ++q) __sincosf(0.5f * ang[q], &s[q], &c[q]);
#pragma unroll
        for (int q = 0; q < 6; ++q) ts[q] = ((l >> (5 - q)) & 1) ? s[q] : -s[q];
    }

    // uniform constants
    const float crc0 = ws[0], crs0 = ws[1], crc1 = ws[2], crs1 = ws[3];
    const float uct0 = ws[4], ust0 = ws[5];
    const float uct1 = ws[8],  ust1 = ws[9],  cl1 = ws[10], sl1 = ws[11], cp1 = ws[12], sp1 = ws[13];
    const float u01r1 = ws[14], u01i1 = ws[15], u10r1 = ws[16], u10i1 = ws[17], u11r1 = ws[18], u11i1 = ws[19];

    // layer-0 fused-U3 diag phases from table (k = b4+b2+b0)
    const int ki = ((l >> 4) & 1) + ((l >> 2) & 1) + (l & 1);
    const float4* dtab = (const float4*)(ws + 20 + ki * 8);
    float4 d0 = dtab[0], d1 = dtab[1];
    const v2 CAB_lm = {d0.x, d0.z}, SAB_lm = {d0.y, d0.w};
    const v2 CAB_ph = {d1.x, d1.z}, SAB_ph = {d1.y, d1.w};
    const float tu1 = ((l >> 4) & 1) ? ust0 : -ust0;
    const float tu3 = ((l >> 2) & 1) ? ust0 : -ust0;
    const float tu5 = (l & 1)        ? ust0 : -ust0;

    // ================= Phase 1 (real, packed A={a0,a1}, B={a2,a3}) =========
    v2 A, B;
    {
        float pl = (((l >> 5) & 1) ? s[0] : c[0]);
        pl *= (((l >> 4) & 1) ? s[1] : c[1]);
        pl *= (((l >> 3) & 1) ? s[2] : c[2]);
        pl *= (((l >> 2) & 1) ? s[3] : c[3]);
        pl *= (((l >> 1) & 1) ? s[4] : c[4]);
        pl *= ((l & 1) ? s[5] : c[5]);
        v2 cs7 = {c[7], s[7]};
        A = sp(pl * c[6]) * cs7;
        B = sp(pl * s[6]) * cs7;
    }
    CNOT_FUSED();
#pragma unroll
    for (int cyc = 0; cyc < 3; ++cyc) {
        RY_L(0, 32); RY_L(1, 16); RY_L(2, 8); RY_L(3, 4); RY_L(4, 2); RY_L(5, 1);
        { // RY q=6: elementwise across A,B
            v2 nA = fma2(sp(-s[6]), B, sp(c[6]) * A);
            B = fma2(sp(c[6]), B, sp(s[6]) * A);
            A = nA;
        }
        { // RY q=7: within-vector
            v2 sv = {-s[7], s[7]};
            A = fma2(sp(c[7]), A, sv * swp(A));
            B = fma2(sp(c[7]), B, sv * swp(B));
        }
        CNOT_FUSED();
    }

    // ================= Phase 2 (complex, packed) ===========================
    v2 Ra = A, Rb = B, Ia = sp(0.f), Ib = sp(0.f);

    // Layer 0, first sublayer: (0,1) real-state fast path, then (2,3),(4,5),(6,7)
    {
        const bool ct = (l >> 5) & 1;
        v2 oRa = sx2<16>(Ra), oRb = sx2<16>(Rb);
        if (ct) {
            Ia = sp(-crs0) * oRa; Ra = sp(crc0) * Ra;
            Ib = sp(-crs0) * oRb; Rb = sp(crc0) * Rb;
        }
    }
    CRX_LL(3, 4, crc0, crs0);          // (2,3)
    CRX_LL(1, 1, crc0, crs0);          // (4,5)
    { // (6,7): in-lane pair on regs (2,3) = within Rb/Ib
        v2 nRb = fma2(sp(crc0), Rb, sp(crs0) * swp(Ib));
        Ib = fma2(sp(crc0), Ib, sp(-crs0) * swp(Rb));   // uses old Rb
        Rb = nRb;
    }
    // second sublayer: (1,2),(3,4),(5,6)
    CRX_LL(4, 8, crc0, crs0);
    CRX_LL(2, 2, crc0, crs0);
    { // (5,6): control lane bit0, pairs (0,2),(1,3): a<->b elementwise
        if (l & 1) {
            v2 nRa = fma2(sp(crc0), Ra, sp(crs0) * Ib);
            v2 nRb = fma2(sp(crc0), Rb, sp(crs0) * Ia);
            v2 nIa = fma2(sp(crc0), Ia, sp(-crs0) * Rb);
            v2 nIb = fma2(sp(crc0), Ib, sp(-crs0) * Ra);
            Ra = nRa; Rb = nRb; Ia = nIa; Ib = nIb;
        }
    }
    // ---- fused layer-0 U3 on q1,q3,q5,q7: [D2][RY x4][D1] ----
    { // D1 (lm0 phases)
        v2 nRa = fma2(CAB_lm, Ra, -SAB_lm * Ia);
        Ia = fma2(CAB_lm, Ia, SAB_lm * Ra); Ra = nRa;
        v2 nRb = fma2(CAB_lm, Rb, -SAB_lm * Ib);
        Ib = fma2(CAB_lm, Ib, SAB_lm * Rb); Rb = nRb;
    }
    RYC0(16, tu1);                     // RY(th0) q=1
    RYC0(4,  tu3);                     // RY(th0) q=3
    RYC0(1,  tu5);                     // RY(th0) q=5
    { // RY(th0) q=7: within-vector, real coefficients
        v2 usv = {-ust0, ust0};
        Ra = fma2(sp(uct0), Ra, usv * swp(Ra));
        Rb = fma2(sp(uct0), Rb, usv * swp(Rb));
        Ia = fma2(sp(uct0), Ia, usv * swp(Ia));
        Ib = fma2(sp(uct0), Ib, usv * swp(Ib));
    }
    { // D2 (ph0 phases)
        v2 nRa = fma2(CAB_ph, Ra, -SAB_ph * Ia);
        Ia = fma2(CAB_ph, Ia, SAB_ph * Ra); Ra = nRa;
        v2 nRb = fma2(CAB_ph, Rb, -SAB_ph * Ib);
        Ib = fma2(CAB_ph, Ib, SAB_ph * Rb); Rb = nRb;
    }

    // Layer 1: CRX (1,3),(5,7) then (3,5); U3 on 3,7
    CRX_LL(4, 4, crc1, crs1);          // (1,3)
    { // (5,7): control lane bit0, within-vector pairs (0,1),(2,3)
        if (l & 1) {
            v2 nRa = fma2(sp(crc1), Ra, sp(crs1) * swp(Ia));
            v2 nIa = fma2(sp(crc1), Ia, sp(-crs1) * swp(Ra));
            v2 nRb = fma2(sp(crc1), Rb, sp(crs1) * swp(Ib));
            v2 nIb = fma2(sp(crc1), Ib, sp(-crs1) * swp(Rb));
            Ra = nRa; Ia = nIa; Rb = nRb; Ib = nIb;
        }
    }
    CRX_LL(2, 1, crc1, crs1);          // (3,5)
    { // U3 layer 1 on q=3 (lane bit2, mask 4): D(lm) RY(th) D(ph)
        const bool b = (l >> 2) & 1;
        if (b) {
            v2 nRa = fma2(sp(cl1), Ra, sp(-sl1) * Ia);
            Ia = fma2(sp(cl1), Ia, sp(sl1) * Ra); Ra = nRa;
            v2 nRb = fma2(sp(cl1), Rb, sp(-sl1) * Ib);
            Ib = fma2(sp(cl1), Ib, sp(sl1) * Rb); Rb = nRb;
        }
        const float t = b ? ust1 : -ust1;
        v2 oRa = sx2<4>(Ra), oIa = sx2<4>(Ia), oRb = sx2<4>(Rb), oIb = sx2<4>(Ib);
        Ra = fma2(sp(uct1), Ra, sp(t) * oRa); Ia = fma2(sp(uct1), Ia, sp(t) * oIa);
        Rb = fma2(sp(uct1), Rb, sp(t) * oRb); Ib = fma2(sp(uct1), Ib, sp(t) * oIb);
        if (b) {
            v2 nRa = fma2(sp(cp1), Ra, sp(-sp1) * Ia);
            Ia = fma2(sp(cp1), Ia, sp(sp1) * Ra); Ra = nRa;
            v2 nRb = fma2(sp(cp1), Rb, sp(-sp1) * Ib);
            Ib = fma2(sp(cp1), Ib, sp(sp1) * Rb); Rb = nRb;
        }
    }
    { // U3 layer 1 on q=7 (j bit0): within-vector complex 2x2
        v2 E0 = {uct1, u11r1}, E1 = {u01r1, u10r1};
        v2 E2 = {0.f, -u11i1}, E3 = {-u01i1, -u10i1};
        v2 G2 = {0.f,  u11i1}, G3 = { u01i1,  u10i1};
        v2 sRa = swp(Ra), sIa = swp(Ia), sRb = swp(Rb), sIb = swp(Ib);
        v2 nRa = fma2(E3, sIa, fma2(E2, Ia, fma2(E1, sRa, E0 * Ra)));
        v2 nIa = fma2(G3, sRa, fma2(G2, Ra, fma2(E1, sIa, E0 * Ia)));
        v2 nRb = fma2(E3, sIb, fma2(E2, Ib, fma2(E1, sRb, E0 * Rb)));
        v2 nIb = fma2(G3, sRb, fma2(G2, Rb, fma2(E1, sIb, E0 * Ib)));
        Ra = nRa; Ia = nIa; Rb = nRb; Ib = nIb;
    }

    // ================= expvals + MLP =================
    v2 Na = fma2(Ia, Ia, Ra * Ra);
    v2 Nb = fma2(Ib, Ib, Rb * Rb);
    v2 T = Na + Nb;
    const float sgn = ((l >> 2) & 1) ? -1.0f : 1.0f;
    v2 F = { sgn * (T.x + T.y), T.x - T.y };   // {Z(q3) term, Z(q7) term}
    F += sx2<1>(F);
    F += sx2<2>(F);
    F += sx2<4>(F);
    F += sx2<8>(F);
    F += sx2<16>(F);
    F += sx2<32>(F);

    // MLP: 10 hidden units on lanes 0..9 of each 16-lane row
    const int k = l & 15;
    float contrib = 0.0f;
    if (k < 10) {
        float z = fmaf(F.x, w1[k], fmaf(F.y, w1[10 + k], b1[k]));
        float e = __expf(2.0f * z);
        float h = (e - 1.0f) / (e + 1.0f);
        contrib = h * w2[k];
    }
    contrib += sx<1>(contrib);
    contrib += sx<2>(contrib);
    contrib += sx<4>(contrib);
    contrib += sx<8>(contrib);
    if (l == 0) {
        float a = contrib + b2[0];
        out[wave] = 1.0f / (1.0f + __expf(-a));
    }
}

extern "C" void kernel_launch(void* const* d_in, const int* in_sizes, int n_in,
                              void* d_out, int out_size, void* d_ws, size_t ws_size,
                              hipStream_t stream) {
    const float* x   = (const float*)d_in[0];
    const float* crx = (const float*)d_in[1];
    const float* u3p = (const float*)d_in[2];
    const float* w1  = (const float*)d_in[3];
    const float* b1  = (const float*)d_in[4];
    const float* w2  = (const float*)d_in[5];
    const float* b2  = (const float*)d_in[6];
    float* out = (float*)d_out;
    float* ws  = (float*)d_ws;

    const int B = in_sizes[0] / NQ;          // 65536
    hipLaunchKernelGGL(qcnn_prep, dim3(1), dim3(64), 0, stream, crx, u3p, ws);
    const int wavesPerBlock = 256 / 64;
    const int grid = (B + wavesPerBlock - 1) / wavesPerBlock;
    hipLaunchKernelGGL(qcnn_kernel, dim3(grid), dim3(256), 0, stream,
                       x, ws, w1, b1, w2, b2, out, B);
}